// Round 11
// baseline (480.254 us; speedup 1.0000x reference)
//
#include <hip/hip_runtime.h>
#include <hip/hip_bf16.h>

#define N_NODES 50000
#define N_EDGES 1600000
#define IN_CH 256
#define NEG_SLOPE 0.2f
#define EPS_F 1e-16f
#define SCAN_BLK 1024
#define N_SCAN_BLKS ((N_NODES + SCAN_BLK - 1) / SCAN_BLK)   // 49
#define DEG_PAD 16   // one 64B line per counter

__device__ __forceinline__ float lrelu(float x) {
    return x > 0.f ? x : NEG_SLOPE * x;
}

// -------- Kernel 0a: detect edge_index storage (int64 vs int32) --------
__global__ __launch_bounds__(256) void k0_detect(const int* __restrict__ ei,
                                                 int* __restrict__ flag)
{
    __shared__ int nz;
    const int t = threadIdx.x;
    if (t == 0) nz = 0;
    __syncthreads();
    if (t & 1) { if (ei[t] != 0) atomicAdd(&nz, 1); }
    __syncthreads();
    if (t == 0) flag[0] = (nz == 0) ? 1 : 0;   // 1 => int64 layout
}

__device__ __forceinline__ int ld_src(const int* ei, int f, int e) {
    return f ? ei[2 * (size_t)e] : ei[e];
}
__device__ __forceinline__ int ld_dst(const int* ei, int f, int e) {
    return f ? ei[2 * (size_t)N_EDGES + 2 * (size_t)e]
             : ei[(size_t)N_EDGES + e];
}

// -------- CSR build step 1: degree count, NON-RETURNING atomics --------
__global__ __launch_bounds__(256) void k_deg(const int* __restrict__ ei,
                                             const int* __restrict__ flag,
                                             int* __restrict__ deg)
{
    const int e = blockIdx.x * 256 + threadIdx.x;
    if (e >= N_EDGES) return;
    const int f = flag[0];
    const int d = ld_dst(ei, f, e);
    atomicAdd(&deg[(size_t)d * DEG_PAD], 1);   // result unused -> fire-and-forget
}

// -------- Hierarchical exclusive scan, phase A (reads padded deg) --------
__global__ __launch_bounds__(SCAN_BLK) void kscanA(const int* __restrict__ deg,
                                                   int* __restrict__ locscan,
                                                   int* __restrict__ blksum)
{
    __shared__ int wsum[SCAN_BLK / 64];
    const int t = threadIdx.x;
    const int i = blockIdx.x * SCAN_BLK + t;
    const int v = (i < N_NODES) ? deg[(size_t)i * DEG_PAD] : 0;
    const int lane = t & 63, w = t >> 6;
    int x = v;
    #pragma unroll
    for (int off = 1; off < 64; off <<= 1) {
        const int y = __shfl_up(x, off);
        if (lane >= off) x += y;
    }
    if (lane == 63) wsum[w] = x;
    __syncthreads();
    if (t < SCAN_BLK / 64) {
        const int wv = wsum[t];
        int xx = wv;
        #pragma unroll
        for (int off = 1; off < SCAN_BLK / 64; off <<= 1) {
            const int y = __shfl_up(xx, off);
            if (t >= off) xx += y;
        }
        wsum[t] = xx - wv;
    }
    __syncthreads();
    const int excl = x - v + wsum[w];
    if (i < N_NODES) locscan[i] = excl;
    if (t == SCAN_BLK - 1) blksum[blockIdx.x] = excl + v;
}

// -------- Phase B: scan block sums (one wave) --------
__global__ __launch_bounds__(64) void kscanB(const int* __restrict__ blksum,
                                             int* __restrict__ blkoff,
                                             int* __restrict__ rowptr)
{
    const int t = threadIdx.x;
    const int v = (t < N_SCAN_BLKS) ? blksum[t] : 0;
    int x = v;
    #pragma unroll
    for (int off = 1; off < 64; off <<= 1) {
        const int y = __shfl_up(x, off);
        if (t >= off) x += y;
    }
    if (t < N_SCAN_BLKS) blkoff[t] = x - v;
    if (t == 63) rowptr[N_NODES] = x;
}

// -------- Phase C: add block offsets; also init fill cursor --------
__global__ __launch_bounds__(256) void kscanC(const int* __restrict__ locscan,
                                              const int* __restrict__ blkoff,
                                              int* __restrict__ rowptr,
                                              int* __restrict__ cursor)
{
    const int i = blockIdx.x * 256 + threadIdx.x;
    if (i < N_NODES) {
        const int r = locscan[i] + blkoff[i >> 10];
        rowptr[i] = r;
        cursor[i] = r;
    }
}

// -------- CSR build step 3: fill via returning atomic on cursor --------
__global__ __launch_bounds__(256) void k_fill(const int* __restrict__ ei,
                                              const int* __restrict__ flag,
                                              int* __restrict__ cursor,
                                              int* __restrict__ csr_src)
{
    const int e = blockIdx.x * 256 + threadIdx.x;
    if (e >= N_EDGES) return;
    const int f = flag[0];
    const int s = ld_src(ei, f, e);
    const int d = ld_dst(ei, f, e);
    const int slot = atomicAdd(&cursor[d], 1);   // absolute CSR position
    csr_src[slot] = s;
}

// ---------------- Kernel 1: h1 = x @ W1 ; a_src1/a_dst1 fused ----------------
__global__ __launch_bounds__(256) void k1_gemm1(
    const float* __restrict__ x, const float* __restrict__ W1,
    const float* __restrict__ att_src1, const float* __restrict__ att_dst1,
    float* __restrict__ h1, float* __restrict__ a_src1, float* __restrict__ a_dst1)
{
    __shared__ float w1s[IN_CH * 32];   // 32 KB
    __shared__ float xs[8][IN_CH];      // 8 KB
    __shared__ float attss[32], attds[32];
    const int t = threadIdx.x;
    for (int i = t; i < IN_CH * 32; i += 256) w1s[i] = W1[i];
    if (t < 32) { attss[t] = att_src1[t]; attds[t] = att_dst1[t]; }
    const int row0 = blockIdx.x * 32;
    const int col = t & 31, rl = t >> 5;
    for (int b = 0; b < 4; ++b) {
        const int rbase = row0 + b * 8;
        {
            const int r = t >> 5, chunk = t & 31;
            const int row = rbase + r;
            float4 v0 = make_float4(0.f, 0.f, 0.f, 0.f), v1 = v0;
            if (row < N_NODES) {
                const float4* p = (const float4*)(x + (size_t)row * IN_CH + chunk * 8);
                v0 = p[0]; v1 = p[1];
            }
            float* xp = &xs[r][chunk * 8];
            xp[0] = v0.x; xp[1] = v0.y; xp[2] = v0.z; xp[3] = v0.w;
            xp[4] = v1.x; xp[5] = v1.y; xp[6] = v1.z; xp[7] = v1.w;
        }
        __syncthreads();
        const int row = rbase + rl;
        float acc = 0.f;
        #pragma unroll 8
        for (int k = 0; k < IN_CH; ++k)
            acc += xs[rl][k] * w1s[k * 32 + col];
        if (row < N_NODES) h1[(size_t)row * 32 + col] = acc;
        const int head = col >> 4, c = col & 15;
        float sa = acc * attss[col];
        float sd = acc * attds[col];
        #pragma unroll
        for (int m = 1; m < 16; m <<= 1) {
            sa += __shfl_xor(sa, m);
            sd += __shfl_xor(sd, m);
        }
        if (c == 0 && row < N_NODES) {
            a_src1[row * 2 + head] = sa;
            a_dst1[row * 2 + head] = sd;
        }
        __syncthreads();
    }
}

// -------- Layer-1 aggregation: deferred norm + 8-way MLP unroll --------
__global__ __launch_bounds__(256) void k_agg1(
    const int* __restrict__ rowptr, const int* __restrict__ csr_src,
    const float* __restrict__ a_src1, const float* __restrict__ a_dst1,
    const float* __restrict__ h1, float* __restrict__ out1)
{
    const int wid = (blockIdx.x * 256 + threadIdx.x) >> 6;   // node id (wave-uniform)
    const int lane = threadIdx.x & 63;
    if (wid >= N_NODES) return;
    const int beg = rowptr[wid], end = rowptr[wid + 1];
    const float2 ad = *(const float2*)(a_dst1 + 2 * (size_t)wid);
    const int slot = lane >> 5, ch = lane & 31;
    const int head = ch >> 4;
    const float adh = head ? ad.y : ad.x;
    const int rep = ((ch & 15) == 0);
    float acc = 0.f, sw = 0.f;
    int i = beg + slot;
    // 8 edges in flight per lane (16 per wave with 2 slots)
    for (; i + 14 < end; i += 16) {
        int s[8]; float a[8], h[8], w[8];
        #pragma unroll
        for (int j = 0; j < 8; ++j) s[j] = csr_src[i + 2 * j];
        #pragma unroll
        for (int j = 0; j < 8; ++j) a[j] = a_src1[2 * (size_t)s[j] + head];
        #pragma unroll
        for (int j = 0; j < 8; ++j) h[j] = h1[(size_t)s[j] * 32 + ch];
        #pragma unroll
        for (int j = 0; j < 8; ++j) w[j] = __expf(lrelu(a[j] + adh));
        float wsum = 0.f;
        #pragma unroll
        for (int j = 0; j < 8; ++j) { wsum += w[j]; acc += w[j] * h[j]; }
        if (rep) sw += wsum;
    }
    for (; i < end; i += 2) {
        const int s = csr_src[i];
        const float w = __expf(lrelu(a_src1[2 * (size_t)s + head] + adh));
        if (rep) sw += w;
        acc += w * h1[(size_t)s * 32 + ch];
    }
    sw += __shfl_xor(sw, 32);
    const float swh = __shfl(sw, head << 4);
    acc += __shfl_xor(acc, 32);
    const float inv = 1.f / (swh + EPS_F);
    if (lane < 32) out1[(size_t)wid * 32 + lane] = acc * inv;
}

// ---------------- Kernel 4: h2 = elu(out1+b1) @ W2 ; a_src2/a_dst2 fused ----------------
__global__ __launch_bounds__(256) void k4_layer2(
    const float* __restrict__ out1, const float* __restrict__ b1,
    const float* __restrict__ W2, const float* __restrict__ att_src2,
    const float* __restrict__ att_dst2,
    float* __restrict__ h2, float* __restrict__ a_src2, float* __restrict__ a_dst2)
{
    __shared__ float act[16][32];
    __shared__ float w2s[32 * 16];
    __shared__ float b1s[32], as2[16], ad2[16];
    const int t = threadIdx.x;
    for (int i = t; i < 512; i += 256) w2s[i] = W2[i];
    if (t < 32) b1s[t] = b1[t];
    if (t < 16) { as2[t] = att_src2[t]; ad2[t] = att_dst2[t]; }
    __syncthreads();
    const int node0 = blockIdx.x * 16;
    for (int i = t; i < 512; i += 256) {
        const int nl = i >> 5, k = i & 31;
        const int row = node0 + nl;
        float v = 0.f;
        if (row < N_NODES) {
            v = out1[(size_t)row * 32 + k] + b1s[k];
            v = v > 0.f ? v : expm1f(v);
        }
        act[nl][k] = v;
    }
    __syncthreads();
    const int nl = t >> 4, j = t & 15;
    const int row = node0 + nl;
    float acc = 0.f;
    #pragma unroll
    for (int k = 0; k < 32; ++k) acc += act[nl][k] * w2s[k * 16 + j];
    if (row < N_NODES) h2[(size_t)row * 16 + j] = acc;
    float sa = acc * as2[j], sd = acc * ad2[j];
    #pragma unroll
    for (int m = 1; m < 16; m <<= 1) { sa += __shfl_xor(sa, m); sd += __shfl_xor(sd, m); }
    if (j == 0 && row < N_NODES) { a_src2[row] = sa; a_dst2[row] = sd; }
}

// -------- Layer-2 aggregation: deferred norm + 8-way MLP unroll --------
__global__ __launch_bounds__(256) void k_agg2(
    const int* __restrict__ rowptr, const int* __restrict__ csr_src,
    const float* __restrict__ a_src2, const float* __restrict__ a_dst2,
    const float* __restrict__ h2, float* __restrict__ out2)
{
    const int wid = (blockIdx.x * 256 + threadIdx.x) >> 6;
    const int lane = threadIdx.x & 63;
    if (wid >= N_NODES) return;
    const int beg = rowptr[wid], end = rowptr[wid + 1];
    const float ad = a_dst2[wid];
    const int slot = lane >> 4, ch = lane & 15;
    const int rep = (ch == 0);
    float acc = 0.f, sw = 0.f;
    int i = beg + slot;
    // 8 edges in flight per lane (32 per wave with 4 slots)
    for (; i + 28 < end; i += 32) {
        int s[8]; float a[8], h[8], w[8];
        #pragma unroll
        for (int j = 0; j < 8; ++j) s[j] = csr_src[i + 4 * j];
        #pragma unroll
        for (int j = 0; j < 8; ++j) a[j] = a_src2[s[j]];
        #pragma unroll
        for (int j = 0; j < 8; ++j) h[j] = h2[(size_t)s[j] * 16 + ch];
        #pragma unroll
        for (int j = 0; j < 8; ++j) w[j] = __expf(lrelu(a[j] + ad));
        float wsum = 0.f;
        #pragma unroll
        for (int j = 0; j < 8; ++j) { wsum += w[j]; acc += w[j] * h[j]; }
        if (rep) sw += wsum;
    }
    for (; i < end; i += 4) {
        const int s = csr_src[i];
        const float w = __expf(lrelu(a_src2[s] + ad));
        if (rep) sw += w;
        acc += w * h2[(size_t)s * 16 + ch];
    }
    #pragma unroll
    for (int m = 1; m < 64; m <<= 1) sw += __shfl_xor(sw, m);
    acc += __shfl_xor(acc, 16);
    acc += __shfl_xor(acc, 32);
    const float inv = 1.f / (sw + EPS_F);
    if (lane < 16) out2[(size_t)wid * 16 + lane] = acc * inv;
}

// -------- k_prep: hoist edge-MLP first layer to nodes --------
__global__ __launch_bounds__(256) void k_prep(
    const float* __restrict__ out2, const float* __restrict__ b2,
    const float* __restrict__ Wm1, const float* __restrict__ bm1,
    float* __restrict__ u, float* __restrict__ v)
{
    __shared__ float wa[16 * 16], wb[16 * 16];
    __shared__ float act[16][17];
    __shared__ float b2s[16], bm1s[16];
    const int t = threadIdx.x;
    if (t < 256) {
        const int k = t >> 4, j = t & 15;
        wa[t] = Wm1[k * 16 + j];
        wb[t] = Wm1[(16 + k) * 16 + j];
    }
    if (t < 16) { b2s[t] = b2[t]; bm1s[t] = bm1[t]; }
    __syncthreads();
    const int node0 = blockIdx.x * 16;
    const int nl = t >> 4, c = t & 15;
    const int row = node0 + nl;
    act[nl][c] = (row < N_NODES) ? out2[(size_t)row * 16 + c] + b2s[c] : 0.f;
    __syncthreads();
    float su = bm1s[c], sv = 0.f;
    #pragma unroll
    for (int k = 0; k < 16; ++k) {
        const float a = act[nl][k];
        su += a * wa[k * 16 + c];
        sv += a * wb[k * 16 + c];
    }
    if (row < N_NODES) {
        u[(size_t)row * 16 + c] = su;
        v[(size_t)row * 16 + c] = sv;
    }
}

// ---------------- Kernel 7 lite: per-edge tail of the MLP ----------------
__global__ __launch_bounds__(256) void k7_lite(
    const int* __restrict__ ei, const int* __restrict__ flag,
    const float* __restrict__ u, const float* __restrict__ v,
    const float* __restrict__ Wm2, const float* __restrict__ bm2,
    float* __restrict__ out)
{
    __shared__ float wm2s[16];
    __shared__ float bm2s;
    const int t = threadIdx.x;
    if (t < 16) wm2s[t] = Wm2[t];
    if (t == 0) bm2s = bm2[0];
    __syncthreads();
    const int e = blockIdx.x * 256 + t;
    if (e >= N_EDGES) return;
    const int f = flag[0];
    const int s = ld_src(ei, f, e);
    const int d = ld_dst(ei, f, e);
    const float4* up = (const float4*)(u + (size_t)s * 16);
    const float4* vp = (const float4*)(v + (size_t)d * 16);
    float fl = bm2s;
    #pragma unroll
    for (int i = 0; i < 4; ++i) {
        const float4 a = up[i];
        const float4 b = vp[i];
        fl += fmaxf(a.x + b.x, 0.f) * wm2s[4 * i + 0];
        fl += fmaxf(a.y + b.y, 0.f) * wm2s[4 * i + 1];
        fl += fmaxf(a.z + b.z, 0.f) * wm2s[4 * i + 2];
        fl += fmaxf(a.w + b.w, 0.f) * wm2s[4 * i + 3];
    }
    out[e] = fmaxf(fl, 0.f);
}

extern "C" void kernel_launch(void* const* d_in, const int* in_sizes, int n_in,
                              void* d_out, int out_size, void* d_ws, size_t ws_size,
                              hipStream_t stream)
{
    const float* x        = (const float*)d_in[0];
    const int*   ei       = (const int*)d_in[1];
    const float* W1       = (const float*)d_in[2];
    const float* att_src1 = (const float*)d_in[3];
    const float* att_dst1 = (const float*)d_in[4];
    const float* b1       = (const float*)d_in[5];
    const float* W2       = (const float*)d_in[6];
    const float* att_src2 = (const float*)d_in[7];
    const float* att_dst2 = (const float*)d_in[8];
    const float* b2       = (const float*)d_in[9];
    const float* Wm1      = (const float*)d_in[10];
    const float* bm1      = (const float*)d_in[11];
    const float* Wm2      = (const float*)d_in[12];
    const float* bm2      = (const float*)d_in[13];

    float* ws = (float*)d_ws;
    size_t off = 0;
    float* h1     = ws + off; off += 32 * (size_t)N_NODES;
    float* a_src1 = ws + off; off += 2  * (size_t)N_NODES;
    float* a_dst1 = ws + off; off += 2  * (size_t)N_NODES;
    float* out1   = ws + off; off += 32 * (size_t)N_NODES;
    float* h2     = ws + off; off += 16 * (size_t)N_NODES;
    float* a_src2 = ws + off; off += 1  * (size_t)N_NODES;
    float* a_dst2 = ws + off; off += 1  * (size_t)N_NODES;
    float* out2   = ws + off; off += 16 * (size_t)N_NODES;
    float* u      = ws + off; off += 16 * (size_t)N_NODES;
    float* v      = ws + off; off += 16 * (size_t)N_NODES;
    int* deg     = (int*)(ws + off); off += (size_t)N_NODES * DEG_PAD;
    int* locscan = (int*)(ws + off); off += (size_t)N_NODES;
    int* rowptr  = (int*)(ws + off); off += (size_t)N_NODES + 16;
    int* cursor  = (int*)(ws + off); off += (size_t)N_NODES + 16;
    int* csr_src = (int*)(ws + off); off += (size_t)N_EDGES;
    int* blksum  = (int*)(ws + off); off += 64;
    int* blkoff  = (int*)(ws + off); off += 64;
    int* flag    = (int*)(ws + off); off += 64;

    hipMemsetAsync(deg, 0, (size_t)N_NODES * DEG_PAD * sizeof(int), stream);

    k0_detect<<<1, 256, 0, stream>>>(ei, flag);
    k_deg<<<(N_EDGES + 255) / 256, 256, 0, stream>>>(ei, flag, deg);
    kscanA<<<N_SCAN_BLKS, SCAN_BLK, 0, stream>>>(deg, locscan, blksum);
    kscanB<<<1, 64, 0, stream>>>(blksum, blkoff, rowptr);
    kscanC<<<(N_NODES + 255) / 256, 256, 0, stream>>>(locscan, blkoff, rowptr, cursor);
    k_fill<<<(N_EDGES + 255) / 256, 256, 0, stream>>>(ei, flag, cursor, csr_src);

    k1_gemm1<<<(N_NODES + 31) / 32, 256, 0, stream>>>(
        x, W1, att_src1, att_dst1, h1, a_src1, a_dst1);
    k_agg1<<<(N_NODES + 3) / 4, 256, 0, stream>>>(
        rowptr, csr_src, a_src1, a_dst1, h1, out1);
    k4_layer2<<<(N_NODES + 15) / 16, 256, 0, stream>>>(
        out1, b1, W2, att_src2, att_dst2, h2, a_src2, a_dst2);
    k_agg2<<<(N_NODES + 3) / 4, 256, 0, stream>>>(
        rowptr, csr_src, a_src2, a_dst2, h2, out2);
    k_prep<<<(N_NODES + 15) / 16, 256, 0, stream>>>(
        out2, b2, Wm1, bm1, u, v);
    k7_lite<<<(N_EDGES + 255) / 256, 256, 0, stream>>>(
        ei, flag, u, v, Wm2, bm2, (float*)d_out);
}

// Round 12
// 375.453 us; speedup vs baseline: 1.2791x; 1.2791x over previous
//
#include <hip/hip_runtime.h>
#include <hip/hip_bf16.h>

#define N_NODES 50000
#define N_EDGES 1600000
#define IN_CH 256
#define NEG_SLOPE 0.2f
#define EPS_F 1e-16f
#define SCAN_BLK 1024
#define N_SCAN_BLKS ((N_NODES + SCAN_BLK - 1) / SCAN_BLK)   // 49
#define NSUB 8            // one sub-histogram per XCD (blockIdx & 7)
#define SUBPITCH 50048    // N_NODES rounded up; keeps sub arrays line-separated

__device__ __forceinline__ float lrelu(float x) {
    return x > 0.f ? x : NEG_SLOPE * x;
}

// -------- Kernel 0a: detect edge_index storage (int64 vs int32) --------
__global__ __launch_bounds__(256) void k0_detect(const int* __restrict__ ei,
                                                 int* __restrict__ flag)
{
    __shared__ int nz;
    const int t = threadIdx.x;
    if (t == 0) nz = 0;
    __syncthreads();
    if (t & 1) { if (ei[t] != 0) atomicAdd(&nz, 1); }
    __syncthreads();
    if (t == 0) flag[0] = (nz == 0) ? 1 : 0;   // 1 => int64 layout
}

__device__ __forceinline__ int ld_src(const int* ei, int f, int e) {
    return f ? ei[2 * (size_t)e] : ei[e];
}
__device__ __forceinline__ int ld_dst(const int* ei, int f, int e) {
    return f ? ei[2 * (size_t)N_EDGES + 2 * (size_t)e]
             : ei[(size_t)N_EDGES + e];
}

// -------- CSR build step 1: XCD-local degree histograms --------
// sub = blockIdx&7 tracks the round-robin workgroup->XCD mapping, so each
// sub-histogram's lines stay owned by one XCD's L2 (no cross-XCD ping-pong).
__global__ __launch_bounds__(256) void k_deg(const int* __restrict__ ei,
                                             const int* __restrict__ flag,
                                             int* __restrict__ deg,
                                             int* __restrict__ eoff)
{
    const int e = blockIdx.x * 256 + threadIdx.x;
    if (e >= N_EDGES) return;
    const int sub = blockIdx.x & (NSUB - 1);
    const int f = flag[0];
    const int d = ld_dst(ei, f, e);
    eoff[e] = atomicAdd(&deg[sub * SUBPITCH + d], 1);
}

// -------- Phase A: per-node sum of 8 sub-counts; in-place sub-prefixes --------
__global__ __launch_bounds__(SCAN_BLK) void kscanA(int* __restrict__ deg,
                                                   int* __restrict__ locscan,
                                                   int* __restrict__ blksum)
{
    __shared__ int wsum[SCAN_BLK / 64];
    const int t = threadIdx.x;
    const int i = blockIdx.x * SCAN_BLK + t;
    int v = 0;
    if (i < N_NODES) {
        int c[NSUB];
        #pragma unroll
        for (int s = 0; s < NSUB; ++s) c[s] = deg[s * SUBPITCH + i];
        int p = 0;
        #pragma unroll
        for (int s = 0; s < NSUB; ++s) {   // exclusive prefix over subs, in place
            deg[s * SUBPITCH + i] = p;
            p += c[s];
        }
        v = p;                              // node degree
    }
    const int lane = t & 63, w = t >> 6;
    int x = v;
    #pragma unroll
    for (int off = 1; off < 64; off <<= 1) {
        const int y = __shfl_up(x, off);
        if (lane >= off) x += y;
    }
    if (lane == 63) wsum[w] = x;
    __syncthreads();
    if (t < SCAN_BLK / 64) {
        const int wv = wsum[t];
        int xx = wv;
        #pragma unroll
        for (int off = 1; off < SCAN_BLK / 64; off <<= 1) {
            const int y = __shfl_up(xx, off);
            if (t >= off) xx += y;
        }
        wsum[t] = xx - wv;
    }
    __syncthreads();
    const int excl = x - v + wsum[w];
    if (i < N_NODES) locscan[i] = excl;
    if (t == SCAN_BLK - 1) blksum[blockIdx.x] = excl + v;
}

// -------- Phase B: scan block sums (one wave) --------
__global__ __launch_bounds__(64) void kscanB(const int* __restrict__ blksum,
                                             int* __restrict__ blkoff,
                                             int* __restrict__ rowptr)
{
    const int t = threadIdx.x;
    const int v = (t < N_SCAN_BLKS) ? blksum[t] : 0;
    int x = v;
    #pragma unroll
    for (int off = 1; off < 64; off <<= 1) {
        const int y = __shfl_up(x, off);
        if (t >= off) x += y;
    }
    if (t < N_SCAN_BLKS) blkoff[t] = x - v;
    if (t == 63) rowptr[N_NODES] = x;
}

// -------- Phase C: rowptr; promote sub-prefixes to absolute sub-bases --------
__global__ __launch_bounds__(256) void kscanC(const int* __restrict__ locscan,
                                              const int* __restrict__ blkoff,
                                              int* __restrict__ rowptr,
                                              int* __restrict__ deg)
{
    const int i = blockIdx.x * 256 + threadIdx.x;
    if (i < N_NODES) {
        const int r = locscan[i] + blkoff[i >> 10];
        rowptr[i] = r;
        #pragma unroll
        for (int s = 0; s < NSUB; ++s) deg[s * SUBPITCH + i] += r;
    }
}

// -------- CSR build step 3: fill, no atomics --------
__global__ __launch_bounds__(256) void k_fill(const int* __restrict__ ei,
                                              const int* __restrict__ flag,
                                              const int* __restrict__ subabs,
                                              const int* __restrict__ eoff,
                                              int* __restrict__ csr_src)
{
    const int e = blockIdx.x * 256 + threadIdx.x;
    if (e >= N_EDGES) return;
    const int sub = blockIdx.x & (NSUB - 1);   // same grid as k_deg -> same sub
    const int f = flag[0];
    const int s = ld_src(ei, f, e);
    const int d = ld_dst(ei, f, e);
    csr_src[subabs[sub * SUBPITCH + d] + eoff[e]] = s;
}

// ---------------- Kernel 1: h1 = x @ W1 ; a_src1/a_dst1 fused ----------------
__global__ __launch_bounds__(256) void k1_gemm1(
    const float* __restrict__ x, const float* __restrict__ W1,
    const float* __restrict__ att_src1, const float* __restrict__ att_dst1,
    float* __restrict__ h1, float* __restrict__ a_src1, float* __restrict__ a_dst1)
{
    __shared__ float w1s[IN_CH * 32];   // 32 KB
    __shared__ float xs[8][IN_CH];      // 8 KB
    __shared__ float attss[32], attds[32];
    const int t = threadIdx.x;
    for (int i = t; i < IN_CH * 32; i += 256) w1s[i] = W1[i];
    if (t < 32) { attss[t] = att_src1[t]; attds[t] = att_dst1[t]; }
    const int row0 = blockIdx.x * 32;
    const int col = t & 31, rl = t >> 5;
    for (int b = 0; b < 4; ++b) {
        const int rbase = row0 + b * 8;
        {
            const int r = t >> 5, chunk = t & 31;
            const int row = rbase + r;
            float4 v0 = make_float4(0.f, 0.f, 0.f, 0.f), v1 = v0;
            if (row < N_NODES) {
                const float4* p = (const float4*)(x + (size_t)row * IN_CH + chunk * 8);
                v0 = p[0]; v1 = p[1];
            }
            float* xp = &xs[r][chunk * 8];
            xp[0] = v0.x; xp[1] = v0.y; xp[2] = v0.z; xp[3] = v0.w;
            xp[4] = v1.x; xp[5] = v1.y; xp[6] = v1.z; xp[7] = v1.w;
        }
        __syncthreads();
        const int row = rbase + rl;
        float acc = 0.f;
        #pragma unroll 8
        for (int k = 0; k < IN_CH; ++k)
            acc += xs[rl][k] * w1s[k * 32 + col];
        if (row < N_NODES) h1[(size_t)row * 32 + col] = acc;
        const int head = col >> 4, c = col & 15;
        float sa = acc * attss[col];
        float sd = acc * attds[col];
        #pragma unroll
        for (int m = 1; m < 16; m <<= 1) {
            sa += __shfl_xor(sa, m);
            sd += __shfl_xor(sd, m);
        }
        if (c == 0 && row < N_NODES) {
            a_src1[row * 2 + head] = sa;
            a_dst1[row * 2 + head] = sd;
        }
        __syncthreads();
    }
}

// -------- Layer-1 aggregation: deferred norm + 8-way MLP unroll --------
__global__ __launch_bounds__(256) void k_agg1(
    const int* __restrict__ rowptr, const int* __restrict__ csr_src,
    const float* __restrict__ a_src1, const float* __restrict__ a_dst1,
    const float* __restrict__ h1, float* __restrict__ out1)
{
    const int wid = (blockIdx.x * 256 + threadIdx.x) >> 6;   // node id (wave-uniform)
    const int lane = threadIdx.x & 63;
    if (wid >= N_NODES) return;
    const int beg = rowptr[wid], end = rowptr[wid + 1];
    const float2 ad = *(const float2*)(a_dst1 + 2 * (size_t)wid);
    const int slot = lane >> 5, ch = lane & 31;
    const int head = ch >> 4;
    const float adh = head ? ad.y : ad.x;
    const int rep = ((ch & 15) == 0);
    float acc = 0.f, sw = 0.f;
    int i = beg + slot;
    for (; i + 14 < end; i += 16) {
        int s[8]; float a[8], h[8], w[8];
        #pragma unroll
        for (int j = 0; j < 8; ++j) s[j] = csr_src[i + 2 * j];
        #pragma unroll
        for (int j = 0; j < 8; ++j) a[j] = a_src1[2 * (size_t)s[j] + head];
        #pragma unroll
        for (int j = 0; j < 8; ++j) h[j] = h1[(size_t)s[j] * 32 + ch];
        #pragma unroll
        for (int j = 0; j < 8; ++j) w[j] = __expf(lrelu(a[j] + adh));
        float wsum = 0.f;
        #pragma unroll
        for (int j = 0; j < 8; ++j) { wsum += w[j]; acc += w[j] * h[j]; }
        if (rep) sw += wsum;
    }
    for (; i < end; i += 2) {
        const int s = csr_src[i];
        const float w = __expf(lrelu(a_src1[2 * (size_t)s + head] + adh));
        if (rep) sw += w;
        acc += w * h1[(size_t)s * 32 + ch];
    }
    sw += __shfl_xor(sw, 32);
    const float swh = __shfl(sw, head << 4);
    acc += __shfl_xor(acc, 32);
    const float inv = 1.f / (swh + EPS_F);
    if (lane < 32) out1[(size_t)wid * 32 + lane] = acc * inv;
}

// ---------------- Kernel 4: h2 = elu(out1+b1) @ W2 ; a_src2/a_dst2 fused ----------------
__global__ __launch_bounds__(256) void k4_layer2(
    const float* __restrict__ out1, const float* __restrict__ b1,
    const float* __restrict__ W2, const float* __restrict__ att_src2,
    const float* __restrict__ att_dst2,
    float* __restrict__ h2, float* __restrict__ a_src2, float* __restrict__ a_dst2)
{
    __shared__ float act[16][32];
    __shared__ float w2s[32 * 16];
    __shared__ float b1s[32], as2[16], ad2[16];
    const int t = threadIdx.x;
    for (int i = t; i < 512; i += 256) w2s[i] = W2[i];
    if (t < 32) b1s[t] = b1[t];
    if (t < 16) { as2[t] = att_src2[t]; ad2[t] = att_dst2[t]; }
    __syncthreads();
    const int node0 = blockIdx.x * 16;
    for (int i = t; i < 512; i += 256) {
        const int nl = i >> 5, k = i & 31;
        const int row = node0 + nl;
        float v = 0.f;
        if (row < N_NODES) {
            v = out1[(size_t)row * 32 + k] + b1s[k];
            v = v > 0.f ? v : expm1f(v);
        }
        act[nl][k] = v;
    }
    __syncthreads();
    const int nl = t >> 4, j = t & 15;
    const int row = node0 + nl;
    float acc = 0.f;
    #pragma unroll
    for (int k = 0; k < 32; ++k) acc += act[nl][k] * w2s[k * 16 + j];
    if (row < N_NODES) h2[(size_t)row * 16 + j] = acc;
    float sa = acc * as2[j], sd = acc * ad2[j];
    #pragma unroll
    for (int m = 1; m < 16; m <<= 1) { sa += __shfl_xor(sa, m); sd += __shfl_xor(sd, m); }
    if (j == 0 && row < N_NODES) { a_src2[row] = sa; a_dst2[row] = sd; }
}

// -------- Layer-2 aggregation: deferred norm + 8-way MLP unroll --------
__global__ __launch_bounds__(256) void k_agg2(
    const int* __restrict__ rowptr, const int* __restrict__ csr_src,
    const float* __restrict__ a_src2, const float* __restrict__ a_dst2,
    const float* __restrict__ h2, float* __restrict__ out2)
{
    const int wid = (blockIdx.x * 256 + threadIdx.x) >> 6;
    const int lane = threadIdx.x & 63;
    if (wid >= N_NODES) return;
    const int beg = rowptr[wid], end = rowptr[wid + 1];
    const float ad = a_dst2[wid];
    const int slot = lane >> 4, ch = lane & 15;
    const int rep = (ch == 0);
    float acc = 0.f, sw = 0.f;
    int i = beg + slot;
    for (; i + 28 < end; i += 32) {
        int s[8]; float a[8], h[8], w[8];
        #pragma unroll
        for (int j = 0; j < 8; ++j) s[j] = csr_src[i + 4 * j];
        #pragma unroll
        for (int j = 0; j < 8; ++j) a[j] = a_src2[s[j]];
        #pragma unroll
        for (int j = 0; j < 8; ++j) h[j] = h2[(size_t)s[j] * 16 + ch];
        #pragma unroll
        for (int j = 0; j < 8; ++j) w[j] = __expf(lrelu(a[j] + ad));
        float wsum = 0.f;
        #pragma unroll
        for (int j = 0; j < 8; ++j) { wsum += w[j]; acc += w[j] * h[j]; }
        if (rep) sw += wsum;
    }
    for (; i < end; i += 4) {
        const int s = csr_src[i];
        const float w = __expf(lrelu(a_src2[s] + ad));
        if (rep) sw += w;
        acc += w * h2[(size_t)s * 16 + ch];
    }
    #pragma unroll
    for (int m = 1; m < 64; m <<= 1) sw += __shfl_xor(sw, m);
    acc += __shfl_xor(acc, 16);
    acc += __shfl_xor(acc, 32);
    const float inv = 1.f / (sw + EPS_F);
    if (lane < 16) out2[(size_t)wid * 16 + lane] = acc * inv;
}

// -------- k_prep: hoist edge-MLP first layer to nodes --------
__global__ __launch_bounds__(256) void k_prep(
    const float* __restrict__ out2, const float* __restrict__ b2,
    const float* __restrict__ Wm1, const float* __restrict__ bm1,
    float* __restrict__ u, float* __restrict__ v)
{
    __shared__ float wa[16 * 16], wb[16 * 16];
    __shared__ float act[16][17];
    __shared__ float b2s[16], bm1s[16];
    const int t = threadIdx.x;
    if (t < 256) {
        const int k = t >> 4, j = t & 15;
        wa[t] = Wm1[k * 16 + j];
        wb[t] = Wm1[(16 + k) * 16 + j];
    }
    if (t < 16) { b2s[t] = b2[t]; bm1s[t] = bm1[t]; }
    __syncthreads();
    const int node0 = blockIdx.x * 16;
    const int nl = t >> 4, c = t & 15;
    const int row = node0 + nl;
    act[nl][c] = (row < N_NODES) ? out2[(size_t)row * 16 + c] + b2s[c] : 0.f;
    __syncthreads();
    float su = bm1s[c], sv = 0.f;
    #pragma unroll
    for (int k = 0; k < 16; ++k) {
        const float a = act[nl][k];
        su += a * wa[k * 16 + c];
        sv += a * wb[k * 16 + c];
    }
    if (row < N_NODES) {
        u[(size_t)row * 16 + c] = su;
        v[(size_t)row * 16 + c] = sv;
    }
}

// ---------------- Kernel 7 lite: per-edge tail of the MLP ----------------
__global__ __launch_bounds__(256) void k7_lite(
    const int* __restrict__ ei, const int* __restrict__ flag,
    const float* __restrict__ u, const float* __restrict__ v,
    const float* __restrict__ Wm2, const float* __restrict__ bm2,
    float* __restrict__ out)
{
    __shared__ float wm2s[16];
    __shared__ float bm2s;
    const int t = threadIdx.x;
    if (t < 16) wm2s[t] = Wm2[t];
    if (t == 0) bm2s = bm2[0];
    __syncthreads();
    const int e = blockIdx.x * 256 + t;
    if (e >= N_EDGES) return;
    const int f = flag[0];
    const int s = ld_src(ei, f, e);
    const int d = ld_dst(ei, f, e);
    const float4* up = (const float4*)(u + (size_t)s * 16);
    const float4* vp = (const float4*)(v + (size_t)d * 16);
    float fl = bm2s;
    #pragma unroll
    for (int i = 0; i < 4; ++i) {
        const float4 a = up[i];
        const float4 b = vp[i];
        fl += fmaxf(a.x + b.x, 0.f) * wm2s[4 * i + 0];
        fl += fmaxf(a.y + b.y, 0.f) * wm2s[4 * i + 1];
        fl += fmaxf(a.z + b.z, 0.f) * wm2s[4 * i + 2];
        fl += fmaxf(a.w + b.w, 0.f) * wm2s[4 * i + 3];
    }
    out[e] = fmaxf(fl, 0.f);
}

extern "C" void kernel_launch(void* const* d_in, const int* in_sizes, int n_in,
                              void* d_out, int out_size, void* d_ws, size_t ws_size,
                              hipStream_t stream)
{
    const float* x        = (const float*)d_in[0];
    const int*   ei       = (const int*)d_in[1];
    const float* W1       = (const float*)d_in[2];
    const float* att_src1 = (const float*)d_in[3];
    const float* att_dst1 = (const float*)d_in[4];
    const float* b1       = (const float*)d_in[5];
    const float* W2       = (const float*)d_in[6];
    const float* att_src2 = (const float*)d_in[7];
    const float* att_dst2 = (const float*)d_in[8];
    const float* b2       = (const float*)d_in[9];
    const float* Wm1      = (const float*)d_in[10];
    const float* bm1      = (const float*)d_in[11];
    const float* Wm2      = (const float*)d_in[12];
    const float* bm2      = (const float*)d_in[13];

    float* ws = (float*)d_ws;
    size_t off = 0;
    float* h1     = ws + off; off += 32 * (size_t)N_NODES;
    float* a_src1 = ws + off; off += 2  * (size_t)N_NODES;
    float* a_dst1 = ws + off; off += 2  * (size_t)N_NODES;
    float* out1   = ws + off; off += 32 * (size_t)N_NODES;
    float* h2     = ws + off; off += 16 * (size_t)N_NODES;
    float* a_src2 = ws + off; off += 1  * (size_t)N_NODES;
    float* a_dst2 = ws + off; off += 1  * (size_t)N_NODES;
    float* out2   = ws + off; off += 16 * (size_t)N_NODES;
    float* u      = ws + off; off += 16 * (size_t)N_NODES;
    float* v      = ws + off; off += 16 * (size_t)N_NODES;
    int* deg     = (int*)(ws + off); off += (size_t)NSUB * SUBPITCH;   // 8 XCD-local histograms
    int* locscan = (int*)(ws + off); off += (size_t)N_NODES;
    int* rowptr  = (int*)(ws + off); off += (size_t)N_NODES + 16;
    int* eoff    = (int*)(ws + off); off += (size_t)N_EDGES;
    int* csr_src = (int*)(ws + off); off += (size_t)N_EDGES;
    int* blksum  = (int*)(ws + off); off += 64;
    int* blkoff  = (int*)(ws + off); off += 64;
    int* flag    = (int*)(ws + off); off += 64;

    hipMemsetAsync(deg, 0, (size_t)NSUB * SUBPITCH * sizeof(int), stream);

    k0_detect<<<1, 256, 0, stream>>>(ei, flag);
    k_deg<<<(N_EDGES + 255) / 256, 256, 0, stream>>>(ei, flag, deg, eoff);
    kscanA<<<N_SCAN_BLKS, SCAN_BLK, 0, stream>>>(deg, locscan, blksum);
    kscanB<<<1, 64, 0, stream>>>(blksum, blkoff, rowptr);
    kscanC<<<(N_NODES + 255) / 256, 256, 0, stream>>>(locscan, blkoff, rowptr, deg);
    k_fill<<<(N_EDGES + 255) / 256, 256, 0, stream>>>(ei, flag, deg, eoff, csr_src);

    k1_gemm1<<<(N_NODES + 31) / 32, 256, 0, stream>>>(
        x, W1, att_src1, att_dst1, h1, a_src1, a_dst1);
    k_agg1<<<(N_NODES + 3) / 4, 256, 0, stream>>>(
        rowptr, csr_src, a_src1, a_dst1, h1, out1);
    k4_layer2<<<(N_NODES + 15) / 16, 256, 0, stream>>>(
        out1, b1, W2, att_src2, att_dst2, h2, a_src2, a_dst2);
    k_agg2<<<(N_NODES + 3) / 4, 256, 0, stream>>>(
        rowptr, csr_src, a_src2, a_dst2, h2, out2);
    k_prep<<<(N_NODES + 15) / 16, 256, 0, stream>>>(
        out2, b2, Wm1, bm1, u, v);
    k7_lite<<<(N_EDGES + 255) / 256, 256, 0, stream>>>(
        ei, flag, u, v, Wm2, bm2, (float*)d_out);
}